// Round 2
// baseline (256.180 us; speedup 1.0000x reference)
//
#include <hip/hip_runtime.h>

#define NL 100
#define BB 8
#define WW 1024
#define HH 1024
#define NPIX (WW * HH)
#define EPSF 1e-7f

// ws layout, 4-byte word offsets
#define OFF_CNT 0      // int  [800]
#define OFF_SX  800    // int  [800]
#define OFF_SY  1600   // int  [800]
#define OFF_MX  2400   // int  [800]  (max x per (b,label), init 0)
#define OFF_MY  3200   // int  [800]
#define OFF_TAB 4000   // float4[800] = (xc, yc, 1/mx, 1/my)  -> 3200 words, byte off 16000 (16B aligned)
#define OFF_INV 7200   // float[2]: inv_fg_den, inv_bg_den
#define WS_WORDS 7202

// One pass over mask: packed u64 histogram (cnt|sx|sy) + int max_x/max_y.
// grid(128, BB) x 256; each wave handles 2048 px -> cnt<=2048 (12b), sx,sy<=2.1M (23b).
__global__ __launch_bounds__(256) void k_stats(const int* __restrict__ mask,
                                               int* __restrict__ ws) {
    __shared__ unsigned long long s_h[4][NL];
    __shared__ int s_mx[4][NL];
    __shared__ int s_my[4][NL];
    const int b  = blockIdx.y;
    const int wv = threadIdx.x >> 6;
    for (int i = threadIdx.x; i < 4 * NL; i += 256) {
        ((unsigned long long*)s_h)[i] = 0ull;
        ((int*)s_mx)[i] = 0;
        ((int*)s_my)[i] = 0;
    }
    __syncthreads();
    const int4* m4 = (const int4*)(mask + (size_t)b * NPIX);
    const int base4 = blockIdx.x * 2048;   // 2048 int4 = 8192 px / block
#pragma unroll
    for (int it = 0; it < 8; ++it) {
        const int i4 = base4 + it * 256 + threadIdx.x;
        const int4 mv = m4[i4];
        const int p  = i4 << 2;
        const int x0 = p & (HH - 1);   // H%4==0: no row wrap inside the quad
        const int y  = p >> 10;
        const int mm[4] = {mv.x, mv.y, mv.z, mv.w};
#pragma unroll
        for (int j = 0; j < 4; ++j) {
            const int m = mm[j];
            const int x = x0 + j;
            atomicAdd(&s_h[wv][m],
                      (1ull << 46) | ((unsigned long long)x << 23) | (unsigned long long)y);
            // read-test-then-atomic: stale/smaller read only causes a redundant atomic
            if (x > s_mx[wv][m]) atomicMax(&s_mx[wv][m], x);
            if (y > s_my[wv][m]) atomicMax(&s_my[wv][m], y);
        }
    }
    __syncthreads();
    for (int i = threadIdx.x; i < NL; i += 256) {
        int c = 0, sx = 0, sy = 0, mx = 0, my = 0;
#pragma unroll
        for (int w = 0; w < 4; ++w) {
            const unsigned long long v = s_h[w][i];
            c  += (int)(v >> 46);
            sx += (int)((v >> 23) & 0x7FFFFFull);
            sy += (int)(v & 0x7FFFFFull);
            mx = max(mx, s_mx[w][i]);
            my = max(my, s_my[w][i]);
        }
        if (c) {
            atomicAdd(&ws[OFF_CNT + b * NL + i], c);
            atomicAdd(&ws[OFF_SX  + b * NL + i], sx);
            atomicAdd(&ws[OFF_SY  + b * NL + i], sy);
        }
        if (mx) atomicMax(&ws[OFF_MX + b * NL + i], mx);
        if (my) atomicMax(&ws[OFF_MY + b * NL + i], my);
    }
}

__global__ void k_final(int* __restrict__ wsi) {
    float* wsf = (float*)wsi;
    const int t = threadIdx.x;
    if (t < BB * NL) {
        const int c = wsi[OFF_CNT + t];
        const float sc = (float)(c > 0 ? c : 1);
        const float xc = (float)wsi[OFF_SX + t] / sc;
        const float yc = (float)wsi[OFF_SY + t] / sc;
        float fmx = (float)wsi[OFF_MX + t] - xc; if (fmx < 0.0f) fmx = 0.0f;
        float fmy = (float)wsi[OFF_MY + t] - yc; if (fmy < 0.0f) fmy = 0.0f;
        float4 e;
        e.x = xc;
        e.y = yc;
        e.z = (fmx == 0.0f) ? 1.0f : 1.0f / fmx;
        e.w = (fmy == 0.0f) ? 1.0f : 1.0f / fmy;
        ((float4*)(wsf + OFF_TAB))[t] = e;
    }
    if (t == 0) {
        long long bg = 0;
        for (int b = 0; b < BB; ++b) bg += wsi[OFF_CNT + b * NL];
        const float n = (float)BB * (float)NPIX;
        const float fg_den = (float)((long long)BB * NPIX - bg) + EPSF * n;
        const float bg_den = (float)bg + EPSF * n;
        wsf[OFF_INV + 0] = 1.0f / fg_den;
        wsf[OFF_INV + 1] = 1.0f / bg_den;
    }
}

// grid(1024, BB) x 256; 1 int4 (4 px) per thread.
__global__ __launch_bounds__(256) void k_loss(const int* __restrict__ mask,
                                              const float* __restrict__ pred,
                                              const float* __restrict__ ig,
                                              const int* __restrict__ ws,
                                              float* __restrict__ out) {
    const float* wsf = (const float*)ws;
    __shared__ float4 s_tab[NL];
    const int b = blockIdx.y;
    if (threadIdx.x < NL) s_tab[threadIdx.x] = ((const float4*)(wsf + OFF_TAB))[b * NL + threadIdx.x];
    __syncthreads();
    const float inv_fg = wsf[OFF_INV + 0];
    const float inv_bg = wsf[OFF_INV + 1];

    const int i4 = blockIdx.x * 256 + threadIdx.x;
    const int4   mv  = ((const int4*)  (mask + (size_t)b * NPIX))[i4];
    const float4 iv  = ((const float4*)(ig   + (size_t)b * NPIX))[i4];
    const float4 pxv = ((const float4*)(pred + (size_t)(2 * b)     * NPIX))[i4];
    const float4 pyv = ((const float4*)(pred + (size_t)(2 * b + 1) * NPIX))[i4];
    const int p  = i4 << 2;
    const float x0 = (float)(p & (HH - 1));
    const float y  = (float)(p >> 10);

    const int*   mm  = (const int*)&mv;
    const float* igs = (const float*)&iv;
    const float* pxs = (const float*)&pxv;
    const float* pys = (const float*)&pyv;
    float4 gxv, gyv;
    float* gxa = (float*)&gxv;
    float* gya = (float*)&gyv;

    float acc = 0.0f;
#pragma unroll
    for (int j = 0; j < 4; ++j) {
        const int m = mm[j];
        float gx = 0.0f, gy = 0.0f, w;
        if (m != 0) {
            const float4 t = s_tab[m];
            gx = (x0 + (float)j - t.x) * t.z;
            gy = (y - t.y) * t.w;
            w = inv_fg;
        } else {
            w = inv_bg;
        }
        w *= igs[j];
        const float dx = pxs[j] - gx;
        const float dy = pys[j] - gy;
        const float ax = fabsf(dx), ay = fabsf(dy);
        const float lx = (ax < 1.0f) ? 0.5f * dx * dx : ax - 0.5f;
        const float ly = (ay < 1.0f) ? 0.5f * dy * dy : ay - 0.5f;
        acc += (lx + ly) * w;
        gxa[j] = gx;
        gya[j] = gy;
    }
    ((float4*)(out + 1 + (size_t)(2 * b)     * NPIX))[i4] = gxv;
    ((float4*)(out + 1 + (size_t)(2 * b + 1) * NPIX))[i4] = gyv;

    // wave + block reduction, one global atomic per block
#pragma unroll
    for (int off = 32; off > 0; off >>= 1) acc += __shfl_down(acc, off, 64);
    __shared__ float s_part[4];
    const int lane = threadIdx.x & 63, wv = threadIdx.x >> 6;
    if (lane == 0) s_part[wv] = acc;
    __syncthreads();
    if (threadIdx.x == 0) atomicAdd(out, s_part[0] + s_part[1] + s_part[2] + s_part[3]);
}

extern "C" void kernel_launch(void* const* d_in, const int* in_sizes, int n_in,
                              void* d_out, int out_size, void* d_ws, size_t ws_size,
                              hipStream_t stream) {
    const float* pred = (const float*)d_in[0];
    const int*   mask = (const int*)d_in[1];
    const float* ig   = (const float*)d_in[2];
    float* out = (float*)d_out;
    int*   ws  = (int*)d_ws;

    hipMemsetAsync(d_ws, 0, WS_WORDS * sizeof(int), stream);
    hipMemsetAsync(d_out, 0, sizeof(float), stream);

    k_stats<<<dim3(128, BB), 256, 0, stream>>>(mask, ws);
    k_final<<<1, 800, 0, stream>>>(ws);
    k_loss<<<dim3(1024, BB), 256, 0, stream>>>(mask, pred, ig, ws, out);
}

// Round 3
// 189.171 us; speedup vs baseline: 1.3542x; 1.3542x over previous
//
#include <hip/hip_runtime.h>

#define NL 100
#define BB 8
#define WW 1024
#define HH 1024
#define NPIX (WW * HH)
#define EPSF 1e-7f

// ws layout, 4-byte word offsets
#define OFF_CNT 0      // int  [800]
#define OFF_SX  800    // int  [800]
#define OFF_SY  1600   // int  [800]
#define OFF_MX  2400   // int  [800]  max x coord per (b,label)
#define OFF_MY  3200   // int  [800]  max y coord per (b,label)
#define OFF_TAB 4000   // float4[800] = (xc, yc, 1/fmx, 1/fmy), byte 16000 (16B aligned)
#define OFF_INV 7200   // float[2]
#define OFF_M8  7216   // u32[BB*NPIX/4] packed u8 labels (byte 28864, 16B aligned)
#define ZERO_WORDS 4000

// Row-oriented stats: wave = one row; (cnt<<21)|sx packed u32 add + u32 max per px.
// grid(128, BB) x 256: block = 8 rows, wave handles rows y0, y0+1.
template<bool EMIT8>
__global__ __launch_bounds__(256) void k_stats(const int* __restrict__ mask,
                                               int* __restrict__ ws,
                                               unsigned* __restrict__ m8) {
    __shared__ unsigned s_cs[4][NL];
    __shared__ unsigned s_mx[4][NL];
    __shared__ unsigned g_cnt[NL], g_sx[NL], g_sy[NL], g_mx[NL], g_my[NL];
    const int b    = blockIdx.y;
    const int wv   = threadIdx.x >> 6;
    const int lane = threadIdx.x & 63;
    for (int i = threadIdx.x; i < NL; i += 256) {
        g_cnt[i] = 0u; g_sx[i] = 0u; g_sy[i] = 0u; g_mx[i] = 0u; g_my[i] = 0u;
    }
    for (int i = lane; i < NL; i += 64) { s_cs[wv][i] = 0u; s_mx[wv][i] = 0u; }
    __syncthreads();

    const int4* m4  = (const int4*)(mask + (size_t)b * NPIX);
    unsigned*   m8b = m8 + (size_t)b * (NPIX / 4);
    const int y0 = blockIdx.x * 8 + wv * 2;

    int4 R[2][4];                       // both rows loaded upfront (MLP)
#pragma unroll
    for (int r = 0; r < 2; ++r)
#pragma unroll
        for (int it = 0; it < 4; ++it)
            R[r][it] = m4[(y0 + r) * 256 + it * 64 + lane];

#pragma unroll
    for (int r = 0; r < 2; ++r) {
        const int y = y0 + r;
#pragma unroll
        for (int it = 0; it < 4; ++it) {
            const int4 mv = R[r][it];
            const int c4 = it * 64 + lane;
            const unsigned x0 = (unsigned)(c4 << 2);
            const unsigned v0 = (1u << 21) + x0;
            atomicAdd(&s_cs[wv][mv.x], v0);     atomicMax(&s_mx[wv][mv.x], x0);
            atomicAdd(&s_cs[wv][mv.y], v0 + 1); atomicMax(&s_mx[wv][mv.y], x0 + 1);
            atomicAdd(&s_cs[wv][mv.z], v0 + 2); atomicMax(&s_mx[wv][mv.z], x0 + 2);
            atomicAdd(&s_cs[wv][mv.w], v0 + 3); atomicMax(&s_mx[wv][mv.w], x0 + 3);
            if (EMIT8)
                m8b[y * 256 + c4] = (unsigned)mv.x | ((unsigned)mv.y << 8) |
                                    ((unsigned)mv.z << 16) | ((unsigned)mv.w << 24);
        }
        // per-row flush of this wave's private tables (no barrier needed)
        for (int e = lane; e < NL; e += 64) {
            const unsigned cs  = s_cs[wv][e];
            const unsigned mx  = s_mx[wv][e];
            const unsigned cnt = cs >> 21;
            if (cnt) {
                atomicAdd(&g_cnt[e], cnt);
                atomicAdd(&g_sx[e],  cs & 0x1FFFFFu);
                atomicAdd(&g_sy[e],  cnt * (unsigned)y);
                atomicMax(&g_my[e], (unsigned)y);
            }
            if (mx) atomicMax(&g_mx[e], mx);
            s_cs[wv][e] = 0u;
            s_mx[wv][e] = 0u;
        }
    }
    __syncthreads();
    for (int e = threadIdx.x; e < NL; e += 256) {
        const unsigned cnt = g_cnt[e];
        if (cnt) {
            atomicAdd(&ws[OFF_CNT + b * NL + e], (int)cnt);
            atomicAdd(&ws[OFF_SX  + b * NL + e], (int)g_sx[e]);
            atomicAdd(&ws[OFF_SY  + b * NL + e], (int)g_sy[e]);
            atomicMax(&ws[OFF_MX  + b * NL + e], (int)g_mx[e]);
            atomicMax(&ws[OFF_MY  + b * NL + e], (int)g_my[e]);
        }
    }
}

__global__ void k_final(int* __restrict__ wsi) {
    float* wsf = (float*)wsi;
    const int t = threadIdx.x;
    if (t < BB * NL) {
        const int c = wsi[OFF_CNT + t];
        const float sc = (float)(c > 0 ? c : 1);
        const float xc = (float)wsi[OFF_SX + t] / sc;
        const float yc = (float)wsi[OFF_SY + t] / sc;
        float fmx = (float)wsi[OFF_MX + t] - xc; if (fmx < 0.0f) fmx = 0.0f;
        float fmy = (float)wsi[OFF_MY + t] - yc; if (fmy < 0.0f) fmy = 0.0f;
        float4 e;
        e.x = xc;
        e.y = yc;
        e.z = (fmx == 0.0f) ? 1.0f : 1.0f / fmx;
        e.w = (fmy == 0.0f) ? 1.0f : 1.0f / fmy;
        ((float4*)(wsf + OFF_TAB))[t] = e;
    }
    if (t == 0) {
        long long bg = 0;
        for (int b = 0; b < BB; ++b) bg += wsi[OFF_CNT + b * NL];
        const float n = (float)BB * (float)NPIX;
        const float fg_den = (float)((long long)BB * NPIX - bg) + EPSF * n;
        const float bg_den = (float)bg + EPSF * n;
        wsf[OFF_INV + 0] = 1.0f / fg_den;
        wsf[OFF_INV + 1] = 1.0f / bg_den;
    }
}

// grid(256, BB) x 256: 4 int4 (16 px) per thread, all loads hoisted for MLP.
template<bool USE8>
__global__ __launch_bounds__(256) void k_loss(const int* __restrict__ mask,
                                              const unsigned* __restrict__ m8,
                                              const float* __restrict__ pred,
                                              const float* __restrict__ ig,
                                              const int* __restrict__ ws,
                                              float* __restrict__ out) {
    const float* wsf = (const float*)ws;
    __shared__ float4 s_tab[NL];
    const int b = blockIdx.y;
    for (int i = threadIdx.x; i < NL; i += 256)
        s_tab[i] = ((const float4*)(wsf + OFF_TAB))[b * NL + i];
    __syncthreads();
    const float inv_fg = wsf[OFF_INV + 0];
    const float inv_bg = wsf[OFF_INV + 1];

    const int4*     mi4 = (const int4*)(mask + (size_t)b * NPIX);
    const unsigned* m8b = m8 + (size_t)b * (NPIX / 4);
    const float4*   ig4 = (const float4*)(ig + (size_t)b * NPIX);
    const float4*   px4 = (const float4*)(pred + (size_t)(2 * b) * NPIX);
    const float4*   py4 = (const float4*)(pred + (size_t)(2 * b + 1) * NPIX);
    float* gx_out = out + 1 + (size_t)(2 * b) * NPIX;
    float* gy_out = out + 1 + (size_t)(2 * b + 1) * NPIX;

    const int base = blockIdx.x * 1024;
    unsigned M8[4]; int4 MI[4]; float4 IV[4], PX[4], PY[4];
#pragma unroll
    for (int it = 0; it < 4; ++it) {
        const int i4 = base + it * 256 + threadIdx.x;
        if (USE8) M8[it] = m8b[i4]; else MI[it] = mi4[i4];
        IV[it] = ig4[i4];
        PX[it] = px4[i4];
        PY[it] = py4[i4];
    }

    float acc = 0.0f;
#pragma unroll
    for (int it = 0; it < 4; ++it) {
        const int i4 = base + it * 256 + threadIdx.x;
        const int p  = i4 << 2;
        const float x0 = (float)(p & (HH - 1));
        const float y  = (float)(p >> 10);
        const float* igs = (const float*)&IV[it];
        const float* pxs = (const float*)&PX[it];
        const float* pys = (const float*)&PY[it];
#pragma unroll
        for (int j = 0; j < 4; ++j) {
            const int m = USE8 ? (int)((M8[it] >> (8 * j)) & 255u)
                               : ((const int*)&MI[it])[j];
            const float4 t = s_tab[m];
            const float fgf = (m != 0) ? 1.0f : 0.0f;
            const float gx = (x0 + (float)j - t.x) * t.z * fgf;
            const float gy = (y - t.y) * t.w * fgf;
            const float w  = ((m != 0) ? inv_fg : inv_bg) * igs[j];
            const float dx = pxs[j] - gx;
            const float dy = pys[j] - gy;
            const float ax = fabsf(dx), ay = fabsf(dy);
            acc += ((ax < 1.0f) ? 0.5f * dx * dx : ax - 0.5f) * w
                 + ((ay < 1.0f) ? 0.5f * dy * dy : ay - 0.5f) * w;
            __builtin_nontemporal_store(gx, &gx_out[p + j]);
            __builtin_nontemporal_store(gy, &gy_out[p + j]);
        }
    }
    // wave + block reduction, one global atomic per block
#pragma unroll
    for (int off = 32; off > 0; off >>= 1) acc += __shfl_down(acc, off, 64);
    __shared__ float s_part[4];
    const int lane = threadIdx.x & 63, wv = threadIdx.x >> 6;
    if (lane == 0) s_part[wv] = acc;
    __syncthreads();
    if (threadIdx.x == 0) atomicAdd(out, s_part[0] + s_part[1] + s_part[2] + s_part[3]);
}

extern "C" void kernel_launch(void* const* d_in, const int* in_sizes, int n_in,
                              void* d_out, int out_size, void* d_ws, size_t ws_size,
                              hipStream_t stream) {
    const float* pred = (const float*)d_in[0];
    const int*   mask = (const int*)d_in[1];
    const float* ig   = (const float*)d_in[2];
    float* out = (float*)d_out;
    int*   ws  = (int*)d_ws;
    unsigned* m8 = (unsigned*)(ws + OFF_M8);

    const size_t need = ((size_t)OFF_M8 + (size_t)BB * (NPIX / 4)) * 4;
    const bool use8 = ws_size >= need;   // ws_size is constant across calls

    hipMemsetAsync(d_ws, 0, ZERO_WORDS * sizeof(int), stream);
    hipMemsetAsync(d_out, 0, sizeof(float), stream);

    if (use8) k_stats<true ><<<dim3(128, BB), 256, 0, stream>>>(mask, ws, m8);
    else      k_stats<false><<<dim3(128, BB), 256, 0, stream>>>(mask, ws, m8);
    k_final<<<1, 800, 0, stream>>>(ws);
    if (use8) k_loss<true ><<<dim3(256, BB), 256, 0, stream>>>(mask, m8, pred, ig, ws, out);
    else      k_loss<false><<<dim3(256, BB), 256, 0, stream>>>(mask, m8, pred, ig, ws, out);
}

// Round 5
// 185.632 us; speedup vs baseline: 1.3800x; 1.0191x over previous
//
#include <hip/hip_runtime.h>

#define NL 100
#define BB 8
#define HH 1024
#define NPIX (1024 * 1024)
#define EPSF 1e-7f
#define NBLK 128          // k_stats x-blocks (8 rows each)

typedef float f4 __attribute__((ext_vector_type(4)));

// ws word offsets
#define OFF_TAB  0        // float4[BB*NL] = (xc, yc, 1/fmx, 1/fmy)  (3200 words)
#define OFF_CNT0 3200     // u32[BB]: count of label 0 per batch
#define OFF_M8   3216     // u32[BB*NPIX/4] packed u8 labels (byte 12864, 16B aligned)

__device__ __forceinline__ int part_idx(int v, int blk, int b, int l) {
    return ((v * NBLK + blk) * BB + b) * NL + l;
}

// Stats pass: wave = 2 rows; per px ONE ds_add of (cnt<<21|sx) and ONE ds_max of
// (1<<21|x) sharing the same operand. Per-row flush to block-level LDS tables,
// block flush = plain stores to a distinct slot (NO global atomics).
template<bool EMIT8>
__global__ __launch_bounds__(256) void k_stats(const int* __restrict__ mask,
                                               unsigned* __restrict__ part,
                                               unsigned* __restrict__ m8) {
    __shared__ unsigned s_t[4][2 * NL];   // per wave: [0..NL)=cs, [NL..2NL)=mx packed
    __shared__ unsigned g_cnt[NL], g_sx[NL], g_sy[NL], g_mx[NL], g_my[NL];
    const int b    = blockIdx.y;
    const int wv   = threadIdx.x >> 6;
    const int lane = threadIdx.x & 63;
    for (int i = threadIdx.x; i < NL; i += 256) {
        g_cnt[i] = 0u; g_sx[i] = 0u; g_sy[i] = 0u; g_mx[i] = 0u; g_my[i] = 0u;
    }
    for (int i = lane; i < 2 * NL; i += 64) s_t[wv][i] = 0u;
    __syncthreads();

    const int4* m4  = (const int4*)(mask + (size_t)b * NPIX);
    unsigned*   m8b = m8 + (size_t)b * (NPIX / 4);
    const int y0 = blockIdx.x * 8 + wv * 2;

    int4 R[2][4];
#pragma unroll
    for (int r = 0; r < 2; ++r)
#pragma unroll
        for (int it = 0; it < 4; ++it)
            R[r][it] = m4[(y0 + r) * 256 + it * 64 + lane];

    unsigned* tp = &s_t[wv][0];
#pragma unroll
    for (int r = 0; r < 2; ++r) {
        const int y = y0 + r;
#pragma unroll
        for (int it = 0; it < 4; ++it) {
            const int4 mv = R[r][it];
            const int c4 = it * 64 + lane;
            const unsigned v0 = (1u << 21) + (unsigned)(c4 << 2);
            { unsigned* p = tp + mv.x; atomicAdd(p, v0);      atomicMax(p + NL, v0); }
            { unsigned* p = tp + mv.y; atomicAdd(p, v0 + 1u); atomicMax(p + NL, v0 + 1u); }
            { unsigned* p = tp + mv.z; atomicAdd(p, v0 + 2u); atomicMax(p + NL, v0 + 2u); }
            { unsigned* p = tp + mv.w; atomicAdd(p, v0 + 3u); atomicMax(p + NL, v0 + 3u); }
            if (EMIT8)
                m8b[y * 256 + c4] = (unsigned)mv.x | ((unsigned)mv.y << 8) |
                                    ((unsigned)mv.z << 16) | ((unsigned)mv.w << 24);
        }
        // per-row flush of this wave's private table (no barrier needed)
        for (int e = lane; e < NL; e += 64) {
            const unsigned cs = tp[e];
            if (cs) {
                const unsigned mxv = tp[e + NL];
                const unsigned cnt = cs >> 21;
                atomicAdd(&g_cnt[e], cnt);
                atomicAdd(&g_sx[e],  cs & 0x1FFFFFu);
                atomicAdd(&g_sy[e],  cnt * (unsigned)y);
                atomicMax(&g_mx[e],  mxv & 0x1FFFFFu);
                atomicMax(&g_my[e],  (unsigned)y);
                tp[e] = 0u;
                tp[e + NL] = 0u;
            }
        }
    }
    __syncthreads();
    const int blk = blockIdx.x;
    for (int e = threadIdx.x; e < NL; e += 256) {
        part[part_idx(0, blk, b, e)] = g_cnt[e];
        part[part_idx(1, blk, b, e)] = g_sx[e];
        part[part_idx(2, blk, b, e)] = g_sy[e];
        part[part_idx(3, blk, b, e)] = g_mx[e];
        part[part_idx(4, blk, b, e)] = g_my[e];
    }
}

// Reduce 128 block-slots per (b,label) -> centroid/max table. grid(BB) x 512.
__global__ __launch_bounds__(512) void k_final(const unsigned* __restrict__ part,
                                               float* __restrict__ wsf) {
    __shared__ unsigned pc[4][NL], psx[4][NL], psy[4][NL], pmx[4][NL], pmy[4][NL];
    const int b = blockIdx.x;
    const int q = threadIdx.x >> 7;     // 0..3, each handles 32 block-slots
    const int l = threadIdx.x & 127;
    if (l < NL) {
        unsigned cnt = 0, sx = 0, sy = 0, mx = 0, my = 0;
#pragma unroll 4
        for (int blk = q * 32; blk < q * 32 + 32; ++blk) {
            cnt += part[part_idx(0, blk, b, l)];
            sx  += part[part_idx(1, blk, b, l)];
            sy  += part[part_idx(2, blk, b, l)];
            mx = max(mx, part[part_idx(3, blk, b, l)]);
            my = max(my, part[part_idx(4, blk, b, l)]);
        }
        pc[q][l] = cnt; psx[q][l] = sx; psy[q][l] = sy; pmx[q][l] = mx; pmy[q][l] = my;
    }
    __syncthreads();
    if (q == 0 && l < NL) {
        const unsigned cnt = pc[0][l] + pc[1][l] + pc[2][l] + pc[3][l];
        const unsigned sx  = psx[0][l] + psx[1][l] + psx[2][l] + psx[3][l];
        const unsigned sy  = psy[0][l] + psy[1][l] + psy[2][l] + psy[3][l];
        const unsigned mx  = max(max(pmx[0][l], pmx[1][l]), max(pmx[2][l], pmx[3][l]));
        const unsigned my  = max(max(pmy[0][l], pmy[1][l]), max(pmy[2][l], pmy[3][l]));
        const float sc = (float)(cnt ? cnt : 1u);
        const float xc = (float)sx / sc;
        const float yc = (float)sy / sc;
        float fmx = (float)mx - xc; if (fmx < 0.0f) fmx = 0.0f;
        float fmy = (float)my - yc; if (fmy < 0.0f) fmy = 0.0f;
        f4 e;
        e.x = xc;
        e.y = yc;
        e.z = (fmx == 0.0f) ? 1.0f : 1.0f / fmx;
        e.w = (fmy == 0.0f) ? 1.0f : 1.0f / fmy;
        ((f4*)(wsf + OFF_TAB))[b * NL + l] = e;
        if (l == 0) ((unsigned*)wsf)[OFF_CNT0 + b] = cnt;   // label-0 count for this b
    }
}

// grid(256, BB) x 256: 16 px/thread, hoisted NT loads, packed NT float4 stores.
template<bool USE8>
__global__ __launch_bounds__(256, 4) void k_loss(const int* __restrict__ mask,
                                                 const unsigned* __restrict__ m8,
                                                 const float* __restrict__ pred,
                                                 const float* __restrict__ ig,
                                                 const float* __restrict__ wsf,
                                                 float* __restrict__ out) {
    __shared__ f4 s_tab[NL];
    __shared__ unsigned s_c0[BB];
    const int b = blockIdx.y;
    for (int i = threadIdx.x; i < NL; i += 256)
        s_tab[i] = ((const f4*)(wsf + OFF_TAB))[b * NL + i];
    if (threadIdx.x < BB) s_c0[threadIdx.x] = ((const unsigned*)wsf)[OFF_CNT0 + threadIdx.x];
    __syncthreads();
    float bgc = 0.0f;
#pragma unroll
    for (int i = 0; i < BB; ++i) bgc += (float)s_c0[i];
    const float n = (float)BB * (float)NPIX;
    const float inv_bg = 1.0f / (bgc + EPSF * n);
    const float inv_fg = 1.0f / ((n - bgc) + EPSF * n);

    const int4*     mi4 = (const int4*)(mask + (size_t)b * NPIX);
    const unsigned* m8b = m8 + (size_t)b * (NPIX / 4);
    const f4*       ig4 = (const f4*)(ig + (size_t)b * NPIX);
    const f4*       px4 = (const f4*)(pred + (size_t)(2 * b) * NPIX);
    const f4*       py4 = (const f4*)(pred + (size_t)(2 * b + 1) * NPIX);
    f4* gx4 = (f4*)(out + 1 + (size_t)(2 * b) * NPIX);      // +4B misaligned: HW-ok
    f4* gy4 = (f4*)(out + 1 + (size_t)(2 * b + 1) * NPIX);

    const int base = blockIdx.x * 1024;
    unsigned M8[4]; int4 MI[4]; f4 IV[4], PX[4], PY[4];
#pragma unroll
    for (int it = 0; it < 4; ++it) {
        const int i4 = base + it * 256 + threadIdx.x;
        if (USE8) M8[it] = m8b[i4]; else MI[it] = mi4[i4];
        IV[it] = __builtin_nontemporal_load(&ig4[i4]);
        PX[it] = __builtin_nontemporal_load(&px4[i4]);
        PY[it] = __builtin_nontemporal_load(&py4[i4]);
    }

    float acc = 0.0f;
#pragma unroll
    for (int it = 0; it < 4; ++it) {
        const int i4 = base + it * 256 + threadIdx.x;
        const int p  = i4 << 2;
        const float x0 = (float)(p & (HH - 1));
        const float y  = (float)(p >> 10);
        const float* igs = (const float*)&IV[it];
        const float* pxs = (const float*)&PX[it];
        const float* pys = (const float*)&PY[it];
        f4 gxv, gyv;
        float* gxa = (float*)&gxv;
        float* gya = (float*)&gyv;
#pragma unroll
        for (int j = 0; j < 4; ++j) {
            const int m = USE8 ? (int)((M8[it] >> (8 * j)) & 255u)
                               : ((const int*)&MI[it])[j];
            const f4 t = s_tab[m];
            const float fgf = (m != 0) ? 1.0f : 0.0f;
            const float gx = (x0 + (float)j - t.x) * t.z * fgf;
            const float gy = (y - t.y) * t.w * fgf;
            const float w  = ((m != 0) ? inv_fg : inv_bg) * igs[j];
            const float dx = pxs[j] - gx;
            const float dy = pys[j] - gy;
            const float ax = fabsf(dx), ay = fabsf(dy);
            acc += ((ax < 1.0f) ? 0.5f * dx * dx : ax - 0.5f) * w
                 + ((ay < 1.0f) ? 0.5f * dy * dy : ay - 0.5f) * w;
            gxa[j] = gx;
            gya[j] = gy;
        }
        __builtin_nontemporal_store(gxv, &gx4[i4]);
        __builtin_nontemporal_store(gyv, &gy4[i4]);
    }
    // wave + block reduction, one global atomic per block
#pragma unroll
    for (int off = 32; off > 0; off >>= 1) acc += __shfl_down(acc, off, 64);
    __shared__ float s_part[4];
    const int lane = threadIdx.x & 63, wv = threadIdx.x >> 6;
    if (lane == 0) s_part[wv] = acc;
    __syncthreads();
    if (threadIdx.x == 0) atomicAdd(out, s_part[0] + s_part[1] + s_part[2] + s_part[3]);
}

extern "C" void kernel_launch(void* const* d_in, const int* in_sizes, int n_in,
                              void* d_out, int out_size, void* d_ws, size_t ws_size,
                              hipStream_t stream) {
    const float* pred = (const float*)d_in[0];
    const int*   mask = (const int*)d_in[1];
    const float* ig   = (const float*)d_in[2];
    float* out = (float*)d_out;
    unsigned* wsu = (unsigned*)d_ws;
    unsigned* m8  = wsu + OFF_M8;

    const size_t part_words = 5ull * NBLK * BB * NL;
    const size_t need8 = ((size_t)OFF_M8 + (size_t)BB * (NPIX / 4) + part_words) * 4;
    const bool use8 = ws_size >= need8;              // constant across calls
    unsigned* part = use8 ? (m8 + (size_t)BB * (NPIX / 4)) : (wsu + OFF_M8);

    (void)hipMemsetAsync(d_out, 0, sizeof(float), stream);  // out[0] = 0 for the loss atomic

    if (use8) k_stats<true ><<<dim3(NBLK, BB), 256, 0, stream>>>(mask, part, m8);
    else      k_stats<false><<<dim3(NBLK, BB), 256, 0, stream>>>(mask, part, m8);
    k_final<<<BB, 512, 0, stream>>>(part, (float*)d_ws);
    if (use8) k_loss<true ><<<dim3(256, BB), 256, 0, stream>>>(mask, m8, pred, ig, (const float*)d_ws, out);
    else      k_loss<false><<<dim3(256, BB), 256, 0, stream>>>(mask, m8, pred, ig, (const float*)d_ws, out);
}

// Round 6
// 178.380 us; speedup vs baseline: 1.4361x; 1.0407x over previous
//
#include <hip/hip_runtime.h>

#define NL 100
#define BB 8
#define HH 1024
#define NPIX (1024 * 1024)
#define EPSF 1e-7f
#define NBLK 128          // k_stats x-blocks (8 rows each)
#define LBLK 2048         // k_loss total blocks (256 x BB)

typedef float f4 __attribute__((ext_vector_type(4)));

// ws word offsets
#define OFF_TAB  0                    // float4[BB*NL] (3200 words)
#define OFF_CNT0 3200                 // u32[BB]
#define OFF_M8   3216                 // u32[BB*NPIX/4] packed u8 labels
#define OFF_PART (OFF_M8 + BB * (NPIX / 4))          // u32[5*NBLK*BB*NL]
#define OFF_LP   (OFF_PART + 5 * NBLK * BB * NL)     // float[LBLK]
#define WS_NEED  ((size_t)(OFF_LP + LBLK) * 4)

__device__ __forceinline__ int part_idx(int v, int blk, int b, int l) {
    return ((v * NBLK + blk) * BB + b) * NL + l;
}

// Stats pass: wave = 2 rows, per-row packed tables (cnt<<21|sx), shared mx table,
// ONE flush per 2 rows. Block partials -> plain stores (no global atomics).
template<bool EMIT8>
__global__ __launch_bounds__(256) void k_stats(const int* __restrict__ mask,
                                               unsigned* __restrict__ part,
                                               unsigned* __restrict__ m8) {
    __shared__ unsigned s_cs[4][2][NL];   // per wave, per row
    __shared__ unsigned s_mx[4][NL];
    __shared__ unsigned g_cnt[NL], g_sx[NL], g_sy[NL], g_mx[NL], g_my[NL];
    const int b    = blockIdx.y;
    const int wv   = threadIdx.x >> 6;
    const int lane = threadIdx.x & 63;
    for (int i = threadIdx.x; i < NL; i += 256) {
        g_cnt[i] = 0u; g_sx[i] = 0u; g_sy[i] = 0u; g_mx[i] = 0u; g_my[i] = 0u;
    }
    for (int i = lane; i < 2 * NL; i += 64) s_cs[wv][0][i] = 0u;   // covers [0] and [1]
    for (int i = lane; i < NL; i += 64) s_mx[wv][i] = 0u;
    __syncthreads();

    const int4* m4  = (const int4*)(mask + (size_t)b * NPIX);
    unsigned*   m8b = m8 + (size_t)b * (NPIX / 4);
    const int y0 = blockIdx.x * 8 + wv * 2;

    int4 R[2][4];
#pragma unroll
    for (int r = 0; r < 2; ++r)
#pragma unroll
        for (int it = 0; it < 4; ++it)
            R[r][it] = m4[(y0 + r) * 256 + it * 64 + lane];

#pragma unroll
    for (int r = 0; r < 2; ++r) {
        unsigned* tp = &s_cs[wv][r][0];
        unsigned* mp = &s_mx[wv][0];
        const int y = y0 + r;
#pragma unroll
        for (int it = 0; it < 4; ++it) {
            const int4 mv = R[r][it];
            const int c4 = it * 64 + lane;
            const unsigned v0 = (1u << 21) + (unsigned)(c4 << 2);
            atomicAdd(tp + mv.x, v0);      atomicMax(mp + mv.x, v0);
            atomicAdd(tp + mv.y, v0 + 1u); atomicMax(mp + mv.y, v0 + 1u);
            atomicAdd(tp + mv.z, v0 + 2u); atomicMax(mp + mv.z, v0 + 2u);
            atomicAdd(tp + mv.w, v0 + 3u); atomicMax(mp + mv.w, v0 + 3u);
            if (EMIT8)
                m8b[y * 256 + c4] = (unsigned)mv.x | ((unsigned)mv.y << 8) |
                                    ((unsigned)mv.z << 16) | ((unsigned)mv.w << 24);
        }
    }
    // single flush for both rows of this wave (no barrier: tables are wave-private)
    for (int e = lane; e < NL; e += 64) {
        const unsigned cs0 = s_cs[wv][0][e];
        const unsigned cs1 = s_cs[wv][1][e];
        const unsigned c0 = cs0 >> 21, c1 = cs1 >> 21;
        const unsigned cnt = c0 + c1;
        if (cnt) {
            atomicAdd(&g_cnt[e], cnt);
            atomicAdd(&g_sx[e], (cs0 & 0x1FFFFFu) + (cs1 & 0x1FFFFFu));
            atomicAdd(&g_sy[e], c0 * (unsigned)y0 + c1 * (unsigned)(y0 + 1));
            atomicMax(&g_my[e], c1 ? (unsigned)(y0 + 1) : (unsigned)y0);
            atomicMax(&g_mx[e], s_mx[wv][e] & 0x1FFFFFu);
        }
    }
    __syncthreads();
    const int blk = blockIdx.x;
    for (int e = threadIdx.x; e < NL; e += 256) {
        part[part_idx(0, blk, b, e)] = g_cnt[e];
        part[part_idx(1, blk, b, e)] = g_sx[e];
        part[part_idx(2, blk, b, e)] = g_sy[e];
        part[part_idx(3, blk, b, e)] = g_mx[e];
        part[part_idx(4, blk, b, e)] = g_my[e];
    }
}

// Reduce 128 block-slots per (b,label) -> centroid/max table. grid(BB) x 512.
__global__ __launch_bounds__(512) void k_final(const unsigned* __restrict__ part,
                                               float* __restrict__ wsf) {
    __shared__ unsigned pc[4][NL], psx[4][NL], psy[4][NL], pmx[4][NL], pmy[4][NL];
    const int b = blockIdx.x;
    const int q = threadIdx.x >> 7;
    const int l = threadIdx.x & 127;
    if (l < NL) {
        unsigned cnt = 0, sx = 0, sy = 0, mx = 0, my = 0;
#pragma unroll 4
        for (int blk = q * 32; blk < q * 32 + 32; ++blk) {
            cnt += part[part_idx(0, blk, b, l)];
            sx  += part[part_idx(1, blk, b, l)];
            sy  += part[part_idx(2, blk, b, l)];
            mx = max(mx, part[part_idx(3, blk, b, l)]);
            my = max(my, part[part_idx(4, blk, b, l)]);
        }
        pc[q][l] = cnt; psx[q][l] = sx; psy[q][l] = sy; pmx[q][l] = mx; pmy[q][l] = my;
    }
    __syncthreads();
    if (q == 0 && l < NL) {
        const unsigned cnt = pc[0][l] + pc[1][l] + pc[2][l] + pc[3][l];
        const unsigned sx  = psx[0][l] + psx[1][l] + psx[2][l] + psx[3][l];
        const unsigned sy  = psy[0][l] + psy[1][l] + psy[2][l] + psy[3][l];
        const unsigned mx  = max(max(pmx[0][l], pmx[1][l]), max(pmx[2][l], pmx[3][l]));
        const unsigned my  = max(max(pmy[0][l], pmy[1][l]), max(pmy[2][l], pmy[3][l]));
        const float sc = (float)(cnt ? cnt : 1u);
        const float xc = (float)sx / sc;
        const float yc = (float)sy / sc;
        float fmx = (float)mx - xc; if (fmx < 0.0f) fmx = 0.0f;
        float fmy = (float)my - yc; if (fmy < 0.0f) fmy = 0.0f;
        f4 e;
        e.x = xc;
        e.y = yc;
        e.z = (fmx == 0.0f) ? 1.0f : 1.0f / fmx;
        e.w = (fmy == 0.0f) ? 1.0f : 1.0f / fmy;
        ((f4*)(wsf + OFF_TAB))[b * NL + l] = e;
        if (l == 0) ((unsigned*)wsf)[OFF_CNT0 + b] = cnt;
    }
}

// grid(256, BB) x 256: 16 px/thread, hoisted NT loads, packed NT float4 stores.
// Per-block loss partial -> plain store to lp[] (no same-address atomic tail).
template<bool USE8>
__global__ __launch_bounds__(256, 4) void k_loss(const int* __restrict__ mask,
                                                 const unsigned* __restrict__ m8,
                                                 const float* __restrict__ pred,
                                                 const float* __restrict__ ig,
                                                 const float* __restrict__ wsf,
                                                 float* __restrict__ lp,
                                                 float* __restrict__ out) {
    __shared__ f4 s_tab[NL];
    __shared__ unsigned s_c0[BB];
    const int b = blockIdx.y;
    for (int i = threadIdx.x; i < NL; i += 256)
        s_tab[i] = ((const f4*)(wsf + OFF_TAB))[b * NL + i];
    if (threadIdx.x < BB) s_c0[threadIdx.x] = ((const unsigned*)wsf)[OFF_CNT0 + threadIdx.x];
    __syncthreads();
    float bgc = 0.0f;
#pragma unroll
    for (int i = 0; i < BB; ++i) bgc += (float)s_c0[i];
    const float n = (float)BB * (float)NPIX;
    const float inv_bg = 1.0f / (bgc + EPSF * n);
    const float inv_fg = 1.0f / ((n - bgc) + EPSF * n);

    const int4*     mi4 = (const int4*)(mask + (size_t)b * NPIX);
    const unsigned* m8b = m8 + (size_t)b * (NPIX / 4);
    const f4*       ig4 = (const f4*)(ig + (size_t)b * NPIX);
    const f4*       px4 = (const f4*)(pred + (size_t)(2 * b) * NPIX);
    const f4*       py4 = (const f4*)(pred + (size_t)(2 * b + 1) * NPIX);
    f4* gx4 = (f4*)(out + 1 + (size_t)(2 * b) * NPIX);      // +4B misaligned: HW-ok
    f4* gy4 = (f4*)(out + 1 + (size_t)(2 * b + 1) * NPIX);

    const int base = blockIdx.x * 1024;
    unsigned M8[4]; int4 MI[4]; f4 IV[4], PX[4], PY[4];
#pragma unroll
    for (int it = 0; it < 4; ++it) {
        const int i4 = base + it * 256 + threadIdx.x;
        if (USE8) M8[it] = m8b[i4]; else MI[it] = mi4[i4];
        IV[it] = __builtin_nontemporal_load(&ig4[i4]);
        PX[it] = __builtin_nontemporal_load(&px4[i4]);
        PY[it] = __builtin_nontemporal_load(&py4[i4]);
    }

    float acc = 0.0f;
#pragma unroll
    for (int it = 0; it < 4; ++it) {
        const int i4 = base + it * 256 + threadIdx.x;
        const int p  = i4 << 2;
        const float x0 = (float)(p & (HH - 1));
        const float y  = (float)(p >> 10);
        const float* igs = (const float*)&IV[it];
        const float* pxs = (const float*)&PX[it];
        const float* pys = (const float*)&PY[it];
        f4 gxv, gyv;
        float* gxa = (float*)&gxv;
        float* gya = (float*)&gyv;
#pragma unroll
        for (int j = 0; j < 4; ++j) {
            const int m = USE8 ? (int)((M8[it] >> (8 * j)) & 255u)
                               : ((const int*)&MI[it])[j];
            const f4 t = s_tab[m];
            const float fgf = (m != 0) ? 1.0f : 0.0f;
            const float gx = (x0 + (float)j - t.x) * t.z * fgf;
            const float gy = (y - t.y) * t.w * fgf;
            const float w  = ((m != 0) ? inv_fg : inv_bg) * igs[j];
            const float dx = pxs[j] - gx;
            const float dy = pys[j] - gy;
            const float ax = fabsf(dx), ay = fabsf(dy);
            acc += ((ax < 1.0f) ? 0.5f * dx * dx : ax - 0.5f) * w
                 + ((ay < 1.0f) ? 0.5f * dy * dy : ay - 0.5f) * w;
            gxa[j] = gx;
            gya[j] = gy;
        }
        __builtin_nontemporal_store(gxv, &gx4[i4]);
        __builtin_nontemporal_store(gyv, &gy4[i4]);
    }
    // wave + block reduction
#pragma unroll
    for (int off = 32; off > 0; off >>= 1) acc += __shfl_down(acc, off, 64);
    __shared__ float s_part[4];
    const int lane = threadIdx.x & 63, wv = threadIdx.x >> 6;
    if (lane == 0) s_part[wv] = acc;
    __syncthreads();
    if (threadIdx.x == 0) {
        const float s = s_part[0] + s_part[1] + s_part[2] + s_part[3];
        if (lp) lp[blockIdx.y * gridDim.x + blockIdx.x] = s;   // plain store, no contention
        else    atomicAdd(out, s);                              // fallback path
    }
}

// Sum LBLK per-block partials -> out[0]. One block.
__global__ __launch_bounds__(256) void k_sum(const float* __restrict__ lp,
                                             float* __restrict__ out) {
    float a = 0.0f;
#pragma unroll
    for (int i = threadIdx.x; i < LBLK; i += 256) a += lp[i];
#pragma unroll
    for (int off = 32; off > 0; off >>= 1) a += __shfl_down(a, off, 64);
    __shared__ float s[4];
    if ((threadIdx.x & 63) == 0) s[threadIdx.x >> 6] = a;
    __syncthreads();
    if (threadIdx.x == 0) out[0] = s[0] + s[1] + s[2] + s[3];
}

extern "C" void kernel_launch(void* const* d_in, const int* in_sizes, int n_in,
                              void* d_out, int out_size, void* d_ws, size_t ws_size,
                              hipStream_t stream) {
    const float* pred = (const float*)d_in[0];
    const int*   mask = (const int*)d_in[1];
    const float* ig   = (const float*)d_in[2];
    float* out = (float*)d_out;
    unsigned* wsu = (unsigned*)d_ws;

    const bool use8 = ws_size >= WS_NEED;   // constant across calls
    unsigned* m8   = wsu + OFF_M8;
    unsigned* part = use8 ? (wsu + OFF_PART) : (wsu + OFF_M8);
    float*    lp   = use8 ? ((float*)wsu + OFF_LP) : nullptr;

    if (!use8) (void)hipMemsetAsync(d_out, 0, sizeof(float), stream);

    if (use8) k_stats<true ><<<dim3(NBLK, BB), 256, 0, stream>>>(mask, part, m8);
    else      k_stats<false><<<dim3(NBLK, BB), 256, 0, stream>>>(mask, part, m8);
    k_final<<<BB, 512, 0, stream>>>(part, (float*)d_ws);
    if (use8) k_loss<true ><<<dim3(256, BB), 256, 0, stream>>>(mask, m8, pred, ig, (const float*)d_ws, lp, out);
    else      k_loss<false><<<dim3(256, BB), 256, 0, stream>>>(mask, m8, pred, ig, (const float*)d_ws, lp, out);
    if (use8) k_sum<<<1, 256, 0, stream>>>(lp, out);
}